// Round 3
// baseline (176.935 us; speedup 1.0000x reference)
//
#include <hip/hip_runtime.h>

// Problem constants (from reference)
#define B 64
#define H 128
#define W 128
#define R 4
#define GW 32
#define N 1024
#define D 16
#define S 32

// R5: 4-way b-split for occupancy. Previous structure was 1024 blocks x 2
// waves = 8 waves/CU (2/SIMD) — too little latency hiding to saturate the
// write path (fill kernel hits 6.9 TB/s at high occupancy; we were at ~2.3
// TB/s effective). The old session's "b-split loses" result was measured
// with NONTEMPORAL loads (cache-bypassing, so sibling pesos re-reads hit
// HBM); with cached loads the 32 MiB pesos is fully absorbed by the 256 MiB
// die-level L3, so HBM traffic stays ~170 MB while parallelism goes 4x.
//
// Chunk-major block indexing: n = blk % N, chunk = blk / N. The 4 siblings
// sharing n's pesos slice are 1024 apart == same (mod 8) slot -> same XCD
// under round-robin dispatch -> pesos L2-reused. All 4096 blocks (16/CU)
// are co-resident, so the reuse window is live.
//
// __launch_bounds__(128, 8): 2 waves/block, 8 waves/SIMD -> 16 blocks/CU;
// forces VGPR <= 64 (per-k diagonal extraction keeps peak pressure ~48).

#define BSPLIT 4
#define BPB (B / BSPLIT)   // 16 b-values per block

typedef float vf4 __attribute__((ext_vector_type(4)));

__global__ __launch_bounds__(128, 8) void conexao_regional_kernel(
    const float* __restrict__ x,       // [B,1,H,W]
    const float* __restrict__ pesos,   // [N,D,S,R,R]
    float* __restrict__ out)           // [B,N,D,S]
{
    __shared__ float sx[BPB][R];  // patch diagonals for this block's b-chunk

    const int blk   = blockIdx.x;
    const int chunk = blk >> 10;        // blk / N  (chunk-major)
    const int n     = blk & (N - 1);    // blk % N
    const int tid   = threadIdx.x;
    const int b0    = chunk * BPB;

    // --- stage xd[b][r] = x[b, 0, i*R+r, j*R+r] into LDS (16 b's only) ---
    const int i = n / GW, j = n % GW;
    const int xbase = i * (R * W) + j * R;
    if (tid < BPB * R) {
        const int b = tid >> 2, r = tid & 3;
        sx[b][r] = x[(b0 + b) * (H * W) + xbase + r * (W + 1)];
    }

    // --- weight diagonals for this thread's 4 elements ---
    // pesos[n,d,s,:,:] is a contiguous 16-float (64 B) block at (n*512+e)*16;
    // diagonal elements sit at offsets 0, 5, 10, 15 within it.
    const int  e0    = tid * 4;                         // element in [0,512)
    const long pbase = ((long)n * 512 + e0) * 16;       // in floats
    float w[4][4];
#pragma unroll
    for (int k = 0; k < 4; ++k) {
        const vf4* p = (const vf4*)(pesos + pbase + (long)k * 16);
        const vf4 q0 = p[0];
        const vf4 q1 = p[1];
        const vf4 q2 = p[2];
        const vf4 q3 = p[3];
        w[k][0] = q0.x;  // [r=0][r=0] -> offset 0
        w[k][1] = q1.y;  // [1][1]     -> offset 5
        w[k][2] = q2.z;  // [2][2]     -> offset 10
        w[k][3] = q3.w;  // [3][3]     -> offset 15
    }
    __syncthreads();

    // --- stream the output: 16 float4 cached stores ---
    float* outp = out + (long)b0 * (N * D * S) + (long)n * 512 + e0;
#pragma unroll
    for (int bb = 0; bb < BPB; ++bb) {
        const vf4 xv = *(const vf4*)&sx[bb][0];   // one ds_read_b128 (broadcast)
        vf4 v;
        v.x = w[0][0] * xv.x + w[0][1] * xv.y + w[0][2] * xv.z + w[0][3] * xv.w;
        v.y = w[1][0] * xv.x + w[1][1] * xv.y + w[1][2] * xv.z + w[1][3] * xv.w;
        v.z = w[2][0] * xv.x + w[2][1] * xv.y + w[2][2] * xv.z + w[2][3] * xv.w;
        v.w = w[3][0] * xv.x + w[3][1] * xv.y + w[3][2] * xv.z + w[3][3] * xv.w;
        *(vf4*)(outp + (long)bb * (N * D * S)) = v;
    }
}

extern "C" void kernel_launch(void* const* d_in, const int* in_sizes, int n_in,
                              void* d_out, int out_size, void* d_ws, size_t ws_size,
                              hipStream_t stream) {
    const float* x     = (const float*)d_in[0];   // [64,1,128,128]
    const float* pesos = (const float*)d_in[1];   // [1024,16,32,4,4]
    float* out = (float*)d_out;                    // [64,1024,16,32]

    conexao_regional_kernel<<<N * BSPLIT, 128, 0, stream>>>(x, pesos, out);
}

// Round 4
// 163.085 us; speedup vs baseline: 1.0849x; 1.0849x over previous
//
#include <hip/hip_runtime.h>

// Problem constants (from reference)
#define B 64
#define H 128
#define W 128
#define R 4
#define GW 32
#define N 1024
#define D 16
#define S 32
// One block per n, 128 threads, each thread owns 4 consecutive (d,s) elements.
// Pesos is read EXACTLY once (R5 proved b-splitting re-reads pesos at a cost
// exactly equal to the extra HBM traffic: +96 MB -> +14 us).
//
// FINAL (R6 = revert to R3): cached loads/stores, minimal traffic.
// Traffic accounting (three-point-verified vs measurements):
//   out 134.2 MB (mandatory) + pesos 33.5 MB (each 64-B line holds its 4
//   diagonal elems at byte offsets 0/20/40/60 -> full line mandatory) +
//   x 4.2 MB = 172 MB  ->  ~25 us at 6.9 TB/s achievable.
//   nt variant   = 272 MB -> 39.4 us (measured delta +14.5 ✓)
//   b-split      = 268 MB -> 38.8 us (measured delta +14.2 ✓)
// The kernel is at the HBM traffic roofline; remaining dur_us is harness
// poison-fill + graph-gap overhead (~138 us constant).

typedef float vf4 __attribute__((ext_vector_type(4)));

__global__ __launch_bounds__(128) void conexao_regional_kernel(
    const float* __restrict__ x,       // [B,1,H,W]
    const float* __restrict__ pesos,   // [N,D,S,R,R]
    float* __restrict__ out)           // [B,N,D,S]
{
    __shared__ float sx[B][R];  // patch diagonals for this block's n (1 KB)

    const int n   = blockIdx.x;
    const int tid = threadIdx.x;

    // --- issue weight loads first (independent of the LDS staging) ---
    // pesos[n,d,s,:,:] is a contiguous 16-float (64 B) block at (n*512+e)*16;
    // diagonal elements sit at offsets 0, 5, 10, 15 within it.
    const int  e0    = tid * 4;                         // element in [0,512)
    const long pbase = ((long)n * 512 + e0) * 16;       // in floats
    vf4 q[4][4];
#pragma unroll
    for (int k = 0; k < 4; ++k) {
        const vf4* p = (const vf4*)(pesos + pbase + (long)k * 16);
        q[k][0] = p[0];
        q[k][1] = p[1];
        q[k][2] = p[2];
        q[k][3] = p[3];
    }

    // --- stage xd[b][r] = x[b, 0, i*R+r, j*R+r] into LDS ---
    // flat addr: b*H*W + (i*R)*W + j*R + r*(W+1)
    const int i = n / GW, j = n % GW;
    const int xbase = i * (R * W) + j * R;
    for (int t = tid; t < B * R; t += 128) {
        const int b = t >> 2, r = t & 3;
        sx[b][r] = x[b * (H * W) + xbase + r * (W + 1)];
    }
    __syncthreads();

    // --- extract weight diagonals ---
    float w[4][4];
#pragma unroll
    for (int k = 0; k < 4; ++k) {
        w[k][0] = q[k][0].x;  // [r=0][r=0] -> offset 0
        w[k][1] = q[k][1].y;  // [1][1]     -> offset 5
        w[k][2] = q[k][2].z;  // [2][2]     -> offset 10
        w[k][3] = q[k][3].w;  // [3][3]     -> offset 15
    }

    // --- stream the output: 64 float4 cached stores ---
    float* outp = out + (long)n * 512 + e0;
#pragma unroll 8
    for (int b = 0; b < B; ++b) {
        const vf4 xv = *(const vf4*)&sx[b][0];   // one ds_read_b128 (broadcast)
        vf4 v;
        v.x = w[0][0] * xv.x + w[0][1] * xv.y + w[0][2] * xv.z + w[0][3] * xv.w;
        v.y = w[1][0] * xv.x + w[1][1] * xv.y + w[1][2] * xv.z + w[1][3] * xv.w;
        v.z = w[2][0] * xv.x + w[2][1] * xv.y + w[2][2] * xv.z + w[2][3] * xv.w;
        v.w = w[3][0] * xv.x + w[3][1] * xv.y + w[3][2] * xv.z + w[3][3] * xv.w;
        *(vf4*)(outp + (long)b * (N * D * S)) = v;
    }
}

extern "C" void kernel_launch(void* const* d_in, const int* in_sizes, int n_in,
                              void* d_out, int out_size, void* d_ws, size_t ws_size,
                              hipStream_t stream) {
    const float* x     = (const float*)d_in[0];   // [64,1,128,128]
    const float* pesos = (const float*)d_in[1];   // [1024,16,32,4,4]
    float* out = (float*)d_out;                    // [64,1024,16,32]

    conexao_regional_kernel<<<N, 128, 0, stream>>>(x, pesos, out);
}